// Round 5
// baseline (271.670 us; speedup 1.0000x reference)
//
#include <hip/hip_runtime.h>

// BahdanauAttention_16518444220431 — diagonal-DP recurrence on MI355X (gfx950).
// R5: chain_kernel re-decomposed. R4 was LDS-BW-bound: every wave read the
// whole 32KB U tile per step (2ot x 64m). Now wave = (otg=w>>1, mhalf=w&1):
// 4ot x 32m -> each wave reads only its 32-row half (16 b128/step, block
// read traffic halved) and each bu feeds 4 MFMAs. W2 A-frags FULLY cached
// (4ot x 16ks = 256 regs; gfx950 unified VGPR/AGPR file, MFMA reads A from
// AGPR) -> zero per-step L2 streaming. launch_bounds stays (256,2): the only
// setting that avoids the 64-VGPR accumulator-spill disaster (R2/R3).

typedef __bf16 bf16x8 __attribute__((ext_vector_type(8)));
typedef __bf16 bf16x4 __attribute__((ext_vector_type(4)));
typedef float f32x16 __attribute__((ext_vector_type(16)));

#define MFMA32(a, b, c) __builtin_amdgcn_mfma_f32_32x32x16_bf16(a, b, c, 0, 0, 0)

__device__ __forceinline__ unsigned short f2bf(float f) {
  unsigned int u = __builtin_bit_cast(unsigned int, f);
  u += 0x7fffu + ((u >> 16) & 1u);
  return (unsigned short)(u >> 16);
}

// ws layout (bf16 elements):
//   [0,65536)        W2 fragments: ((ot*16+ks)*64+lane)*8+j ; o=ot*32+(lane&31), k=ks*16+(lane>>5)*8+j
//   [65536,131072)   W4 fragments, same permutation
//   [131072,135168)  W1-extra frags: lanes<32: j<4 -> W1[o][j], j==4 -> b1[o]+b2[o], else 0
//   [135168,139264)  W3-extra frags: j==4 -> b3[o]+2*b4[o]
//   [139264, +2*512*32768)  chain states: [chain][tile512][2048 int4] (swizzled chunk layout)
#define STATE_OFF 139264

__global__ void prep_kernel(const float* __restrict__ W1, const float* __restrict__ b1,
                            const float* __restrict__ W2, const float* __restrict__ b2,
                            const float* __restrict__ W3, const float* __restrict__ b3,
                            const float* __restrict__ W4, const float* __restrict__ b4,
                            unsigned short* __restrict__ ws) {
  int idx = blockIdx.x * 256 + threadIdx.x;
  if (idx >= 139264) return;
  float v = 0.0f;
  if (idx < 131072) {
    const float* W = (idx < 65536) ? W2 : W4;
    int i = idx & 65535;
    int j = i & 7, f = i >> 3;
    int lane = f & 63, slot = f >> 6;
    int ks = slot & 15, ot = slot >> 4;
    int o = ot * 32 + (lane & 31);
    int k = ks * 16 + (lane >> 5) * 8 + j;
    v = W[o * 256 + k];
  } else {
    int i = idx - 131072;
    bool first = (i < 4096);
    int ii = i & 4095;
    int j = ii & 7, f = ii >> 3;
    int lane = f & 63, ot = f >> 6;
    int o = ot * 32 + (lane & 31);
    if (lane < 32) {
      if (j < 4) v = first ? W1[o * 4 + j] : W3[o * 4 + j];
      else if (j == 4) v = first ? (b1[o] + b2[o]) : (b3[o] + 2.0f * b4[o]);
    }
  }
  ws[idx] = f2bf(v);
}

__global__ __launch_bounds__(256, 2)
void chain_kernel(const float* __restrict__ x, unsigned short* __restrict__ ws) {
  // U: 64 rows x 32 16B-chunks (256 bf16/row), chunk XOR-swizzled by (row&7)
  __shared__ int4 U[64 * 32];
  __shared__ int4 xw[80];   // [x0,x1,x2,x3,1,0,0,0] bf16 chunks for rows j0-8 .. j0+71
  __shared__ int4 zc;

  const int tid = threadIdx.x;
  const int l = tid & 63;
  const int w = tid >> 6;
  const int lane31 = l & 31;
  const int khalf = l >> 5;
  const int otg = w >> 1;      // o-tile group: ot = otg*4 + i, i<4
  const int mhalf = w & 1;     // which 32-row half of U this wave computes/reads
  const int phase = blockIdx.x >> 9;           // 0 = up, 1 = down
  const int tile = blockIdx.x & 511;
  const int b = tile >> 5;
  const int j0 = (tile & 31) * 64;

  const int4* w2f = (const int4*)ws;
  const int4* w1xg = (const int4*)(ws + 131072);

  if (tid == 0) zc = make_int4(0, 0, 0, 0);
  if (tid < 80) {
    int j = j0 - 8 + tid;
    int4 c = make_int4(0, 0, 0, 0);
    if (j >= 0 && j < 2048) {
      const float* xb = x + (b * 4) * 2048 + j;
      unsigned short h0 = f2bf(xb[0]);
      unsigned short h1 = f2bf(xb[2048]);
      unsigned short h2 = f2bf(xb[4096]);
      unsigned short h3 = f2bf(xb[6144]);
      c = make_int4((int)(h0 | ((unsigned int)h1 << 16)),
                    (int)(h2 | ((unsigned int)h3 << 16)),
                    0x00003f80, 0);  // chunk[4] = bf16(1.0) multiplies the bias row
    }
    xw[tid] = c;
  }

  // Full A cache: 4 ot x 16 ks W2 fragments (256 regs, unified VGPR/AGPR file)
  bf16x8 w2c[4][16];
  bf16x8 w1x[4];
#pragma unroll
  for (int i = 0; i < 4; ++i) {
    int ot = otg * 4 + i;
    w1x[i] = __builtin_bit_cast(bf16x8, w1xg[ot * 64 + l]);
#pragma unroll
    for (int ks = 0; ks < 16; ++ks)
      w2c[i][ks] = __builtin_bit_cast(bf16x8, w2f[(ot * 16 + ks) * 64 + l]);
  }
  __syncthreads();

  const int mrow = mhalf * 32 + lane31;   // B-operand n / C-output col

#pragma unroll 1
  for (int t = 1; t <= 8; ++t) {
    f32x16 acc[4] = {};
    // ---- extra K=16 step: adds a[pos] + bias (zero chunk beyond seq edges) ----
    {
      int widx = (phase == 0) ? (mrow + t - 1) : (mrow + 17 - t);
      const int4* p = (l < 32) ? (xw + widx) : (&zc);
      bf16x8 bx = __builtin_bit_cast(bf16x8, *p);
#pragma unroll
      for (int i = 0; i < 4; ++i) acc[i] = MFMA32(w1x[i], bx, acc[i]);
    }
    // ---- main GEMM over previous state (skip at t=1: state is zero) ----
    if (t > 1) {
#pragma unroll
      for (int ks = 0; ks < 16; ++ks) {
        int c0 = 2 * ks + khalf;
        bf16x8 bu = __builtin_bit_cast(bf16x8, U[mrow * 32 + (c0 ^ (mrow & 7))]);
        acc[0] = MFMA32(w2c[0][ks], bu, acc[0]);
        acc[1] = MFMA32(w2c[1][ks], bu, acc[1]);
        acc[2] = MFMA32(w2c[2][ks], bu, acc[2]);
        acc[3] = MFMA32(w2c[3][ks], bu, acc[3]);
      }
    }
    __syncthreads();
    // ---- relu + bf16 pack + swizzled writeback (C layout: col=m, row=o) ----
#pragma unroll
    for (int i = 0; i < 4; ++i) {
      int ot = otg * 4 + i;
#pragma unroll
      for (int q = 0; q < 4; ++q) {
        bf16x4 h;
        h.x = (__bf16)fmaxf(acc[i][4 * q + 0], 0.0f);
        h.y = (__bf16)fmaxf(acc[i][4 * q + 1], 0.0f);
        h.z = (__bf16)fmaxf(acc[i][4 * q + 2], 0.0f);
        h.w = (__bf16)fmaxf(acc[i][4 * q + 3], 0.0f);
        int co = ot * 4 + q;
        int coff = mrow * 32 + (co ^ (mrow & 7));
        *(uint2*)((char*)(U + coff) + khalf * 8) = __builtin_bit_cast(uint2, h);
      }
    }
    __syncthreads();
  }

  // ---- dump final shifted state (verbatim swizzled layout) to workspace ----
  int4* stg = (int4*)(ws + STATE_OFF) + (phase * 512 + tile) * 2048;
#pragma unroll
  for (int i = 0; i < 8; ++i) stg[i * 256 + tid] = U[i * 256 + tid];
}

__global__ __launch_bounds__(256, 2)
void final_kernel(const float* __restrict__ x, const unsigned short* __restrict__ ws,
                  float* __restrict__ out) {
  __shared__ int4 S[2][64 * 32];  // sup / sdown tiles, swizzled chunk layout
  __shared__ int4 xw[64];         // rows j0..j0+63 (always in-range)
  __shared__ int4 zc;

  const int tid = threadIdx.x;
  const int l = tid & 63;
  const int w = tid >> 6;
  const int lane31 = l & 31;
  const int khalf = l >> 5;
  const int tile = blockIdx.x;
  const int b = tile >> 5;
  const int j0 = (tile & 31) * 64;

  const int4* w4f = (const int4*)(ws + 65536);
  const int4* w3xg = (const int4*)(ws + 135168);
  const int4* stg = (const int4*)(ws + STATE_OFF);

  if (tid == 0) zc = make_int4(0, 0, 0, 0);
  if (tid < 64) {
    int j = j0 + tid;
    const float* xb = x + (b * 4) * 2048 + j;
    unsigned short h0 = f2bf(xb[0]);
    unsigned short h1 = f2bf(xb[2048]);
    unsigned short h2 = f2bf(xb[4096]);
    unsigned short h3 = f2bf(xb[6144]);
    xw[tid] = make_int4((int)(h0 | ((unsigned int)h1 << 16)),
                        (int)(h2 | ((unsigned int)h3 << 16)),
                        0x00003f80, 0);
  }
#pragma unroll
  for (int i = 0; i < 8; ++i) {
    S[0][i * 256 + tid] = stg[tile * 2048 + i * 256 + tid];
    S[1][i * 256 + tid] = stg[(512 + tile) * 2048 + i * 256 + tid];
  }
  __syncthreads();

  const int ot0 = w * 2;
  const int mrow0 = lane31;
  const int mrow1 = 32 + lane31;

  f32x16 acc[2][2] = {};
  bf16x8 w3x0 = __builtin_bit_cast(bf16x8, w3xg[ot0 * 64 + l]);
  bf16x8 w3x1 = __builtin_bit_cast(bf16x8, w3xg[(ot0 + 1) * 64 + l]);
#pragma unroll
  for (int mt = 0; mt < 2; ++mt) {
    int m = mt ? mrow1 : mrow0;
    const int4* p = (l < 32) ? (xw + m) : (&zc);
    bf16x8 bx = __builtin_bit_cast(bf16x8, *p);
    acc[mt][0] = MFMA32(w3x0, bx, acc[mt][0]);
    acc[mt][1] = MFMA32(w3x1, bx, acc[mt][1]);
  }
#pragma unroll 1
  for (int ph = 0; ph < 2; ++ph) {
    const int4* Sp = S[ph];
#pragma unroll
    for (int ks = 0; ks < 16; ++ks) {
      int c0 = 2 * ks + khalf;
      bf16x8 bu0 = __builtin_bit_cast(bf16x8, Sp[mrow0 * 32 + (c0 ^ (mrow0 & 7))]);
      bf16x8 bu1 = __builtin_bit_cast(bf16x8, Sp[mrow1 * 32 + (c0 ^ (mrow1 & 7))]);
      bf16x8 af0 = __builtin_bit_cast(bf16x8, w4f[(ot0 * 16 + ks) * 64 + l]);
      bf16x8 af1 = __builtin_bit_cast(bf16x8, w4f[((ot0 + 1) * 16 + ks) * 64 + l]);
      acc[0][0] = MFMA32(af0, bu0, acc[0][0]);
      acc[0][1] = MFMA32(af1, bu0, acc[0][1]);
      acc[1][0] = MFMA32(af0, bu1, acc[1][0]);
      acc[1][1] = MFMA32(af1, bu1, acc[1][1]);
    }
  }
#pragma unroll
  for (int mt = 0; mt < 2; ++mt) {
    int m = mt ? mrow1 : mrow0;
    int pbase = (b * 2048 + j0 + m) * 256;
#pragma unroll
    for (int t2 = 0; t2 < 2; ++t2) {
#pragma unroll
      for (int q = 0; q < 4; ++q) {
        int ob = (ot0 + t2) * 32 + 8 * q + 4 * khalf;
        float4 v;
        v.x = fmaxf(acc[mt][t2][4 * q + 0], 0.0f);
        v.y = fmaxf(acc[mt][t2][4 * q + 1], 0.0f);
        v.z = fmaxf(acc[mt][t2][4 * q + 2], 0.0f);
        v.w = fmaxf(acc[mt][t2][4 * q + 3], 0.0f);
        *(float4*)(out + pbase + ob) = v;
      }
    }
  }
}

extern "C" void kernel_launch(void* const* d_in, const int* in_sizes, int n_in,
                              void* d_out, int out_size, void* d_ws, size_t ws_size,
                              hipStream_t stream) {
  const float* x  = (const float*)d_in[0];
  const float* W1 = (const float*)d_in[1];
  const float* b1 = (const float*)d_in[2];
  const float* W2 = (const float*)d_in[3];
  const float* b2 = (const float*)d_in[4];
  const float* W3 = (const float*)d_in[5];
  const float* b3 = (const float*)d_in[6];
  const float* W4 = (const float*)d_in[7];
  const float* b4 = (const float*)d_in[8];
  unsigned short* ws = (unsigned short*)d_ws;

  prep_kernel<<<544, 256, 0, stream>>>(W1, b1, W2, b2, W3, b3, W4, b4, ws);
  chain_kernel<<<1024, 256, 0, stream>>>(x, ws);
  final_kernel<<<512, 256, 0, stream>>>(x, ws, (float*)d_out);
}

// Round 6
// 155.922 us; speedup vs baseline: 1.7423x; 1.7423x over previous
//
#include <hip/hip_runtime.h>

// BahdanauAttention_16518444220431 — diagonal-DP recurrence on MI355X (gfx950).
// R6 = R4 base (proven 63.5us chain) + two fixes:
//  (a) U stored TRANSPOSED chunk-major: U[chunk*64+row]. GEMM reads become
//      stride-1 over 32 contiguous 16B chunks per half-wave -> conflict-free
//      (R4's row-major XOR swizzle left 4-way conflicts, 5.77M cycles).
//  (b) W2 VGPR cache cut 8->6 ks (-16 regs): unified regs 120+64 -> ~168
//      <= 512/3 -> 3 waves/EU (R4's 184 rounded to 2 waves/EU, 19% occ).
// REGISTER LEDGER (per wave, unified VGPR+AGPR, cap = 512/waves_per_EU):
//   acc 4xf32x16 = 64 AGPR; w2c[2][6] = 48; w1x[2] = 8; bu/addr/misc ~45.
// LESSONS: launch_bounds must stay (256,2) — tighter caps VGPR at 64 and
// spills the accumulator (R2/R3: FETCH 10MB->400MB). A-cache beyond ~48 regs
// spills (R5: w2c[4][16]=256 regs, FETCH 443MB).

typedef __bf16 bf16x8 __attribute__((ext_vector_type(8)));
typedef __bf16 bf16x4 __attribute__((ext_vector_type(4)));
typedef float f32x16 __attribute__((ext_vector_type(16)));

#define MFMA32(a, b, c) __builtin_amdgcn_mfma_f32_32x32x16_bf16(a, b, c, 0, 0, 0)

__device__ __forceinline__ unsigned short f2bf(float f) {
  unsigned int u = __builtin_bit_cast(unsigned int, f);
  u += 0x7fffu + ((u >> 16) & 1u);
  return (unsigned short)(u >> 16);
}

// ws layout (bf16 elements):
//   [0,65536)        W2 fragments: ((ot*16+ks)*64+lane)*8+j ; o=ot*32+(lane&31), k=ks*16+(lane>>5)*8+j
//   [65536,131072)   W4 fragments, same permutation
//   [131072,135168)  W1-extra frags: lanes<32: j<4 -> W1[o][j], j==4 -> b1[o]+b2[o], else 0
//   [135168,139264)  W3-extra frags: j==4 -> b3[o]+2*b4[o]
//   [139264, +2*512*32768)  chain states: [chain][tile512][2048 int4] (chunk-major layout)
#define STATE_OFF 139264

__global__ void prep_kernel(const float* __restrict__ W1, const float* __restrict__ b1,
                            const float* __restrict__ W2, const float* __restrict__ b2,
                            const float* __restrict__ W3, const float* __restrict__ b3,
                            const float* __restrict__ W4, const float* __restrict__ b4,
                            unsigned short* __restrict__ ws) {
  int idx = blockIdx.x * 256 + threadIdx.x;
  if (idx >= 139264) return;
  float v = 0.0f;
  if (idx < 131072) {
    const float* W = (idx < 65536) ? W2 : W4;
    int i = idx & 65535;
    int j = i & 7, f = i >> 3;
    int lane = f & 63, slot = f >> 6;
    int ks = slot & 15, ot = slot >> 4;
    int o = ot * 32 + (lane & 31);
    int k = ks * 16 + (lane >> 5) * 8 + j;
    v = W[o * 256 + k];
  } else {
    int i = idx - 131072;
    bool first = (i < 4096);
    int ii = i & 4095;
    int j = ii & 7, f = ii >> 3;
    int lane = f & 63, ot = f >> 6;
    int o = ot * 32 + (lane & 31);
    if (lane < 32) {
      if (j < 4) v = first ? W1[o * 4 + j] : W3[o * 4 + j];
      else if (j == 4) v = first ? (b1[o] + b2[o]) : (b3[o] + 2.0f * b4[o]);
    }
  }
  ws[idx] = f2bf(v);
}

__global__ __launch_bounds__(256, 2)
void chain_kernel(const float* __restrict__ x, unsigned short* __restrict__ ws) {
  // U, chunk-major: U[c*64 + r] = bf16 elements [8c..8c+7] of row r's state.
  __shared__ int4 U[32 * 64];
  __shared__ int4 xw[80];   // [x0,x1,x2,x3,1,0,0,0] bf16 chunks for rows j0-8 .. j0+71
  __shared__ int4 zc;

  const int tid = threadIdx.x;
  const int l = tid & 63;
  const int w = tid >> 6;
  const int lane31 = l & 31;
  const int khalf = l >> 5;
  const int phase = blockIdx.x >> 9;           // 0 = up, 1 = down
  const int tile = blockIdx.x & 511;
  const int b = tile >> 5;
  const int j0 = (tile & 31) * 64;

  const int4* w2f = (const int4*)ws;
  const int4* w1xg = (const int4*)(ws + 131072);

  if (tid == 0) zc = make_int4(0, 0, 0, 0);
  if (tid < 80) {
    int j = j0 - 8 + tid;
    int4 c = make_int4(0, 0, 0, 0);
    if (j >= 0 && j < 2048) {
      const float* xb = x + (b * 4) * 2048 + j;
      unsigned short h0 = f2bf(xb[0]);
      unsigned short h1 = f2bf(xb[2048]);
      unsigned short h2 = f2bf(xb[4096]);
      unsigned short h3 = f2bf(xb[6144]);
      c = make_int4((int)(h0 | ((unsigned int)h1 << 16)),
                    (int)(h2 | ((unsigned int)h3 << 16)),
                    0x00003f80, 0);  // chunk[4] = bf16(1.0) multiplies the bias row
    }
    xw[tid] = c;
  }

  const int ot0 = w * 2;
  bf16x8 w2c[2][6];
  bf16x8 w1x[2];
#pragma unroll
  for (int t2 = 0; t2 < 2; ++t2) {
    w1x[t2] = __builtin_bit_cast(bf16x8, w1xg[(ot0 + t2) * 64 + l]);
#pragma unroll
    for (int ks = 0; ks < 6; ++ks)
      w2c[t2][ks] = __builtin_bit_cast(bf16x8, w2f[((ot0 + t2) * 16 + ks) * 64 + l]);
  }
  __syncthreads();

  const int mrow0 = lane31;
  const int mrow1 = 32 + lane31;

#pragma unroll 1
  for (int t = 1; t <= 8; ++t) {
    f32x16 acc[2][2] = {};
    // ---- extra K=16 step: adds a[pos] + bias (zero chunk beyond seq edges) ----
#pragma unroll
    for (int mt = 0; mt < 2; ++mt) {
      int m = mt ? mrow1 : mrow0;
      int widx = (phase == 0) ? (m + t - 1) : (m + 17 - t);
      const int4* p = (l < 32) ? (xw + widx) : (&zc);
      bf16x8 bx = __builtin_bit_cast(bf16x8, *p);
      acc[mt][0] = MFMA32(w1x[0], bx, acc[mt][0]);
      acc[mt][1] = MFMA32(w1x[1], bx, acc[mt][1]);
    }
    // ---- main GEMM over previous state (skip at t=1: state is zero) ----
    if (t > 1) {
#pragma unroll
      for (int ks = 0; ks < 16; ++ks) {
        int c0 = 2 * ks + khalf;
        bf16x8 bu0 = __builtin_bit_cast(bf16x8, U[c0 * 64 + mrow0]);
        bf16x8 bu1 = __builtin_bit_cast(bf16x8, U[c0 * 64 + mrow1]);
        bf16x8 af0, af1;
        if (ks < 6) { af0 = w2c[0][ks]; af1 = w2c[1][ks]; }
        else {
          af0 = __builtin_bit_cast(bf16x8, w2f[(ot0 * 16 + ks) * 64 + l]);
          af1 = __builtin_bit_cast(bf16x8, w2f[((ot0 + 1) * 16 + ks) * 64 + l]);
        }
        acc[0][0] = MFMA32(af0, bu0, acc[0][0]);
        acc[0][1] = MFMA32(af1, bu0, acc[0][1]);
        acc[1][0] = MFMA32(af0, bu1, acc[1][0]);
        acc[1][1] = MFMA32(af1, bu1, acc[1][1]);
      }
    }
    __syncthreads();
    // ---- relu + bf16 pack + chunk-major writeback (C layout: col=m, row=o) ----
#pragma unroll
    for (int mt = 0; mt < 2; ++mt) {
      int row = mt ? mrow1 : mrow0;   // m (sequence row)
#pragma unroll
      for (int t2 = 0; t2 < 2; ++t2) {
        int ot = ot0 + t2;
#pragma unroll
        for (int q = 0; q < 4; ++q) {
          bf16x4 h;
          h.x = (__bf16)fmaxf(acc[mt][t2][4 * q + 0], 0.0f);
          h.y = (__bf16)fmaxf(acc[mt][t2][4 * q + 1], 0.0f);
          h.z = (__bf16)fmaxf(acc[mt][t2][4 * q + 2], 0.0f);
          h.w = (__bf16)fmaxf(acc[mt][t2][4 * q + 3], 0.0f);
          int idx = (ot * 4 + q) * 64 + row;   // chunk-major, conflict-free
          *(uint2*)((char*)(U + idx) + khalf * 8) = __builtin_bit_cast(uint2, h);
        }
      }
    }
    __syncthreads();
  }

  // ---- dump final shifted state (verbatim chunk-major layout) to workspace ----
  int4* stg = (int4*)(ws + STATE_OFF) + (phase * 512 + tile) * 2048;
#pragma unroll
  for (int i = 0; i < 8; ++i) stg[i * 256 + tid] = U[i * 256 + tid];
}

__global__ __launch_bounds__(256, 2)
void final_kernel(const float* __restrict__ x, const unsigned short* __restrict__ ws,
                  float* __restrict__ out) {
  __shared__ int4 S[2][32 * 64];  // sup / sdown tiles, chunk-major layout
  __shared__ int4 xw[64];         // rows j0..j0+63 (always in-range)
  __shared__ int4 zc;

  const int tid = threadIdx.x;
  const int l = tid & 63;
  const int w = tid >> 6;
  const int lane31 = l & 31;
  const int khalf = l >> 5;
  const int tile = blockIdx.x;
  const int b = tile >> 5;
  const int j0 = (tile & 31) * 64;

  const int4* w4f = (const int4*)(ws + 65536);
  const int4* w3xg = (const int4*)(ws + 135168);
  const int4* stg = (const int4*)(ws + STATE_OFF);

  if (tid == 0) zc = make_int4(0, 0, 0, 0);
  if (tid < 64) {
    int j = j0 + tid;
    const float* xb = x + (b * 4) * 2048 + j;
    unsigned short h0 = f2bf(xb[0]);
    unsigned short h1 = f2bf(xb[2048]);
    unsigned short h2 = f2bf(xb[4096]);
    unsigned short h3 = f2bf(xb[6144]);
    xw[tid] = make_int4((int)(h0 | ((unsigned int)h1 << 16)),
                        (int)(h2 | ((unsigned int)h3 << 16)),
                        0x00003f80, 0);
  }
#pragma unroll
  for (int i = 0; i < 8; ++i) {
    S[0][i * 256 + tid] = stg[tile * 2048 + i * 256 + tid];
    S[1][i * 256 + tid] = stg[(512 + tile) * 2048 + i * 256 + tid];
  }
  __syncthreads();

  const int ot0 = w * 2;
  const int mrow0 = lane31;
  const int mrow1 = 32 + lane31;

  f32x16 acc[2][2] = {};
  bf16x8 w3x0 = __builtin_bit_cast(bf16x8, w3xg[ot0 * 64 + l]);
  bf16x8 w3x1 = __builtin_bit_cast(bf16x8, w3xg[(ot0 + 1) * 64 + l]);
#pragma unroll
  for (int mt = 0; mt < 2; ++mt) {
    int m = mt ? mrow1 : mrow0;
    const int4* p = (l < 32) ? (xw + m) : (&zc);
    bf16x8 bx = __builtin_bit_cast(bf16x8, *p);
    acc[mt][0] = MFMA32(w3x0, bx, acc[mt][0]);
    acc[mt][1] = MFMA32(w3x1, bx, acc[mt][1]);
  }
#pragma unroll 1
  for (int ph = 0; ph < 2; ++ph) {
    const int4* Sp = S[ph];
#pragma unroll
    for (int ks = 0; ks < 16; ++ks) {
      int c0 = 2 * ks + khalf;
      bf16x8 bu0 = __builtin_bit_cast(bf16x8, Sp[c0 * 64 + mrow0]);
      bf16x8 bu1 = __builtin_bit_cast(bf16x8, Sp[c0 * 64 + mrow1]);
      bf16x8 af0 = __builtin_bit_cast(bf16x8, w4f[(ot0 * 16 + ks) * 64 + l]);
      bf16x8 af1 = __builtin_bit_cast(bf16x8, w4f[((ot0 + 1) * 16 + ks) * 64 + l]);
      acc[0][0] = MFMA32(af0, bu0, acc[0][0]);
      acc[0][1] = MFMA32(af1, bu0, acc[0][1]);
      acc[1][0] = MFMA32(af0, bu1, acc[1][0]);
      acc[1][1] = MFMA32(af1, bu1, acc[1][1]);
    }
  }
#pragma unroll
  for (int mt = 0; mt < 2; ++mt) {
    int m = mt ? mrow1 : mrow0;
    int pbase = (b * 2048 + j0 + m) * 256;
#pragma unroll
    for (int t2 = 0; t2 < 2; ++t2) {
#pragma unroll
      for (int q = 0; q < 4; ++q) {
        int ob = (ot0 + t2) * 32 + 8 * q + 4 * khalf;
        float4 v;
        v.x = fmaxf(acc[mt][t2][4 * q + 0], 0.0f);
        v.y = fmaxf(acc[mt][t2][4 * q + 1], 0.0f);
        v.z = fmaxf(acc[mt][t2][4 * q + 2], 0.0f);
        v.w = fmaxf(acc[mt][t2][4 * q + 3], 0.0f);
        *(float4*)(out + pbase + ob) = v;
      }
    }
  }
}

extern "C" void kernel_launch(void* const* d_in, const int* in_sizes, int n_in,
                              void* d_out, int out_size, void* d_ws, size_t ws_size,
                              hipStream_t stream) {
  const float* x  = (const float*)d_in[0];
  const float* W1 = (const float*)d_in[1];
  const float* b1 = (const float*)d_in[2];
  const float* W2 = (const float*)d_in[3];
  const float* b2 = (const float*)d_in[4];
  const float* W3 = (const float*)d_in[5];
  const float* b3 = (const float*)d_in[6];
  const float* W4 = (const float*)d_in[7];
  const float* b4 = (const float*)d_in[8];
  unsigned short* ws = (unsigned short*)d_ws;

  prep_kernel<<<544, 256, 0, stream>>>(W1, b1, W2, b2, W3, b3, W4, b4, ws);
  chain_kernel<<<1024, 256, 0, stream>>>(x, ws);
  final_kernel<<<512, 256, 0, stream>>>(x, ws, (float*)d_out);
}

// Round 7
// 135.071 us; speedup vs baseline: 2.0113x; 1.1544x over previous
//
#include <hip/hip_runtime.h>

// BahdanauAttention_16518444220431 — diagonal-DP recurrence on MI355X (gfx950).
// R7: FULLY FUSED single block per 64-row tile: up+down chains share the step
// loop (same streamed W2 A-fragments serve both phases), and the final
// W3x+W4*up+W4*down GEMM runs in-block (both states in LDS) — final_kernel
// and the 32MB state round-trip eliminated. 512 blocks = exactly 2/CU, one
// round of 8 sequential steps (R6 had ~16 sequential step-slots).
// REGISTER LEDGER (cap 256 @ 2 waves/EU): acc 2ph*2ot*2mt = 128 AGPR,
// w2c[2][6] = 48, w1x 8, working ~40 -> ~224. LESSONS: launch_bounds stays
// (256,2) (tighter spills acc: R2/R3); A-cache beyond ~48 regs spills (R5).

typedef __bf16 bf16x8 __attribute__((ext_vector_type(8)));
typedef __bf16 bf16x4 __attribute__((ext_vector_type(4)));
typedef float f32x16 __attribute__((ext_vector_type(16)));

#define MFMA32(a, b, c) __builtin_amdgcn_mfma_f32_32x32x16_bf16(a, b, c, 0, 0, 0)

__device__ __forceinline__ unsigned short f2bf(float f) {
  unsigned int u = __builtin_bit_cast(unsigned int, f);
  u += 0x7fffu + ((u >> 16) & 1u);
  return (unsigned short)(u >> 16);
}

// ws layout (bf16 elements):
//   [0,65536)        W2 fragments: ((ot*16+ks)*64+lane)*8+j ; o=ot*32+(lane&31), k=ks*16+(lane>>5)*8+j
//   [65536,131072)   W4 fragments, same permutation
//   [131072,135168)  W1-extra frags: lanes<32: j<4 -> W1[o][j], j==4 -> b1[o]+b2[o], else 0
//   [135168,139264)  W3-extra frags: j==4 -> b3[o]+2*b4[o]
__global__ void prep_kernel(const float* __restrict__ W1, const float* __restrict__ b1,
                            const float* __restrict__ W2, const float* __restrict__ b2,
                            const float* __restrict__ W3, const float* __restrict__ b3,
                            const float* __restrict__ W4, const float* __restrict__ b4,
                            unsigned short* __restrict__ ws) {
  int idx = blockIdx.x * 256 + threadIdx.x;
  if (idx >= 139264) return;
  float v = 0.0f;
  if (idx < 131072) {
    const float* W = (idx < 65536) ? W2 : W4;
    int i = idx & 65535;
    int j = i & 7, f = i >> 3;
    int lane = f & 63, slot = f >> 6;
    int ks = slot & 15, ot = slot >> 4;
    int o = ot * 32 + (lane & 31);
    int k = ks * 16 + (lane >> 5) * 8 + j;
    v = W[o * 256 + k];
  } else {
    int i = idx - 131072;
    bool first = (i < 4096);
    int ii = i & 4095;
    int j = ii & 7, f = ii >> 3;
    int lane = f & 63, ot = f >> 6;
    int o = ot * 32 + (lane & 31);
    if (lane < 32) {
      if (j < 4) v = first ? W1[o * 4 + j] : W3[o * 4 + j];
      else if (j == 4) v = first ? (b1[o] + b2[o]) : (b3[o] + 2.0f * b4[o]);
    }
  }
  ws[idx] = f2bf(v);
}

#define NC 6  // W2 ks cached in regs; ks NC..15 streamed from L2 each step

__global__ __launch_bounds__(256, 2)
void chain_kernel(const float* __restrict__ x, const unsigned short* __restrict__ ws,
                  float* __restrict__ out) {
  // U[ph], chunk-major: U[ph][c*64 + r] = bf16 elems [8c..8c+7] of row r.
  __shared__ int4 U[2][32 * 64];
  __shared__ int4 xw[80];   // [x0,x1,x2,x3,1,0,0,0] bf16 chunks, rows j0-8 .. j0+71
  __shared__ int4 zc;

  const int tid = threadIdx.x;
  const int l = tid & 63;
  const int w = tid >> 6;
  const int lane31 = l & 31;
  const int khalf = l >> 5;
  const int tile = blockIdx.x;
  const int b = tile >> 5;
  const int j0 = (tile & 31) * 64;

  const int4* w2f = (const int4*)ws;
  const int4* w4f = (const int4*)(ws + 65536);
  const int4* w1xg = (const int4*)(ws + 131072);
  const int4* w3xg = (const int4*)(ws + 135168);

  if (tid == 0) zc = make_int4(0, 0, 0, 0);
  if (tid < 80) {
    int j = j0 - 8 + tid;
    int4 c = make_int4(0, 0, 0, 0);
    if (j >= 0 && j < 2048) {
      const float* xb = x + (b * 4) * 2048 + j;
      unsigned short h0 = f2bf(xb[0]);
      unsigned short h1 = f2bf(xb[2048]);
      unsigned short h2 = f2bf(xb[4096]);
      unsigned short h3 = f2bf(xb[6144]);
      c = make_int4((int)(h0 | ((unsigned int)h1 << 16)),
                    (int)(h2 | ((unsigned int)h3 << 16)),
                    0x00003f80, 0);  // chunk[4] = bf16(1.0) multiplies the bias row
    }
    xw[tid] = c;
  }

  const int ot0 = w * 2;
  bf16x8 w2c[2][NC];
  bf16x8 w1x[2];
#pragma unroll
  for (int t2 = 0; t2 < 2; ++t2) {
    w1x[t2] = __builtin_bit_cast(bf16x8, w1xg[(ot0 + t2) * 64 + l]);
#pragma unroll
    for (int ks = 0; ks < NC; ++ks)
      w2c[t2][ks] = __builtin_bit_cast(bf16x8, w2f[((ot0 + t2) * 16 + ks) * 64 + l]);
  }
  __syncthreads();

  const int mrow0 = lane31;
  const int mrow1 = 32 + lane31;

#pragma unroll 1
  for (int t = 1; t <= 8; ++t) {
    f32x16 acc[2][2][2] = {};   // [phase][mt][ot]
    // ---- extra K=16 step: adds a[pos] + bias (zero chunk beyond seq edges) ----
#pragma unroll
    for (int ph = 0; ph < 2; ++ph) {
#pragma unroll
      for (int mt = 0; mt < 2; ++mt) {
        int m = mt ? mrow1 : mrow0;
        int widx = (ph == 0) ? (m + t - 1) : (m + 17 - t);
        const int4* p = (l < 32) ? (xw + widx) : (&zc);
        bf16x8 bx = __builtin_bit_cast(bf16x8, *p);
        acc[ph][mt][0] = MFMA32(w1x[0], bx, acc[ph][mt][0]);
        acc[ph][mt][1] = MFMA32(w1x[1], bx, acc[ph][mt][1]);
      }
    }
    // ---- main GEMM over previous state, both phases share A (skip t=1) ----
    if (t > 1) {
#pragma unroll
      for (int ks = 0; ks < 16; ++ks) {
        int c0 = 2 * ks + khalf;
        bf16x8 bu00 = __builtin_bit_cast(bf16x8, U[0][c0 * 64 + mrow0]);
        bf16x8 bu01 = __builtin_bit_cast(bf16x8, U[0][c0 * 64 + mrow1]);
        bf16x8 bu10 = __builtin_bit_cast(bf16x8, U[1][c0 * 64 + mrow0]);
        bf16x8 bu11 = __builtin_bit_cast(bf16x8, U[1][c0 * 64 + mrow1]);
        bf16x8 af0, af1;
        if (ks < NC) { af0 = w2c[0][ks]; af1 = w2c[1][ks]; }
        else {
          af0 = __builtin_bit_cast(bf16x8, w2f[(ot0 * 16 + ks) * 64 + l]);
          af1 = __builtin_bit_cast(bf16x8, w2f[((ot0 + 1) * 16 + ks) * 64 + l]);
        }
        acc[0][0][0] = MFMA32(af0, bu00, acc[0][0][0]);
        acc[0][0][1] = MFMA32(af1, bu00, acc[0][0][1]);
        acc[0][1][0] = MFMA32(af0, bu01, acc[0][1][0]);
        acc[0][1][1] = MFMA32(af1, bu01, acc[0][1][1]);
        acc[1][0][0] = MFMA32(af0, bu10, acc[1][0][0]);
        acc[1][0][1] = MFMA32(af1, bu10, acc[1][0][1]);
        acc[1][1][0] = MFMA32(af0, bu11, acc[1][1][0]);
        acc[1][1][1] = MFMA32(af1, bu11, acc[1][1][1]);
      }
    }
    __syncthreads();
    // ---- relu + bf16 pack + chunk-major writeback, both phases ----
#pragma unroll
    for (int ph = 0; ph < 2; ++ph) {
#pragma unroll
      for (int mt = 0; mt < 2; ++mt) {
        int row = mt ? mrow1 : mrow0;
#pragma unroll
        for (int t2 = 0; t2 < 2; ++t2) {
          int ot = ot0 + t2;
#pragma unroll
          for (int q = 0; q < 4; ++q) {
            bf16x4 h;
            h.x = (__bf16)fmaxf(acc[ph][mt][t2][4 * q + 0], 0.0f);
            h.y = (__bf16)fmaxf(acc[ph][mt][t2][4 * q + 1], 0.0f);
            h.z = (__bf16)fmaxf(acc[ph][mt][t2][4 * q + 2], 0.0f);
            h.w = (__bf16)fmaxf(acc[ph][mt][t2][4 * q + 3], 0.0f);
            int idx = (ot * 4 + q) * 64 + row;
            *(uint2*)((char*)(U[ph] + idx) + khalf * 8) = __builtin_bit_cast(uint2, h);
          }
        }
      }
    }
    __syncthreads();
  }

  // ---- final: miu^T = relu(W3x + b3 + 2b4 + W4*U0 + W4*U1), in-block ----
  {
    f32x16 acc[2][2] = {};   // [mt][ot]
    bf16x8 w3x0 = __builtin_bit_cast(bf16x8, w3xg[ot0 * 64 + l]);
    bf16x8 w3x1 = __builtin_bit_cast(bf16x8, w3xg[(ot0 + 1) * 64 + l]);
#pragma unroll
    for (int mt = 0; mt < 2; ++mt) {
      int m = mt ? mrow1 : mrow0;
      const int4* p = (l < 32) ? (xw + m + 8) : (&zc);
      bf16x8 bx = __builtin_bit_cast(bf16x8, *p);
      acc[mt][0] = MFMA32(w3x0, bx, acc[mt][0]);
      acc[mt][1] = MFMA32(w3x1, bx, acc[mt][1]);
    }
#pragma unroll 1
    for (int ph = 0; ph < 2; ++ph) {
      const int4* Sp = U[ph];
#pragma unroll
      for (int ks = 0; ks < 16; ++ks) {
        int c0 = 2 * ks + khalf;
        bf16x8 bu0 = __builtin_bit_cast(bf16x8, Sp[c0 * 64 + mrow0]);
        bf16x8 bu1 = __builtin_bit_cast(bf16x8, Sp[c0 * 64 + mrow1]);
        bf16x8 af0 = __builtin_bit_cast(bf16x8, w4f[(ot0 * 16 + ks) * 64 + l]);
        bf16x8 af1 = __builtin_bit_cast(bf16x8, w4f[((ot0 + 1) * 16 + ks) * 64 + l]);
        acc[0][0] = MFMA32(af0, bu0, acc[0][0]);
        acc[0][1] = MFMA32(af1, bu0, acc[0][1]);
        acc[1][0] = MFMA32(af0, bu1, acc[1][0]);
        acc[1][1] = MFMA32(af1, bu1, acc[1][1]);
      }
    }
#pragma unroll
    for (int mt = 0; mt < 2; ++mt) {
      int m = mt ? mrow1 : mrow0;
      int pbase = (b * 2048 + j0 + m) * 256;
#pragma unroll
      for (int t2 = 0; t2 < 2; ++t2) {
#pragma unroll
        for (int q = 0; q < 4; ++q) {
          int ob = (ot0 + t2) * 32 + 8 * q + 4 * khalf;
          float4 v;
          v.x = fmaxf(acc[mt][t2][4 * q + 0], 0.0f);
          v.y = fmaxf(acc[mt][t2][4 * q + 1], 0.0f);
          v.z = fmaxf(acc[mt][t2][4 * q + 2], 0.0f);
          v.w = fmaxf(acc[mt][t2][4 * q + 3], 0.0f);
          *(float4*)(out + pbase + ob) = v;
        }
      }
    }
  }
}

extern "C" void kernel_launch(void* const* d_in, const int* in_sizes, int n_in,
                              void* d_out, int out_size, void* d_ws, size_t ws_size,
                              hipStream_t stream) {
  const float* x  = (const float*)d_in[0];
  const float* W1 = (const float*)d_in[1];
  const float* b1 = (const float*)d_in[2];
  const float* W2 = (const float*)d_in[3];
  const float* b2 = (const float*)d_in[4];
  const float* W3 = (const float*)d_in[5];
  const float* b3 = (const float*)d_in[6];
  const float* W4 = (const float*)d_in[7];
  const float* b4 = (const float*)d_in[8];
  unsigned short* ws = (unsigned short*)d_ws;

  prep_kernel<<<544, 256, 0, stream>>>(W1, b1, W2, b2, W3, b3, W4, b4, ws);
  chain_kernel<<<512, 256, 0, stream>>>(x, ws, (float*)d_out);
}